// Round 23
// baseline (171.539 us; speedup 1.0000x reference)
//
#include <hip/hip_runtime.h>

#define NB 8
#define TT 8192
#define NN 256
#define CH 64             // chunk length (== GEMM M-tile)
#define BT (NB*TT)        // 65536 rows total
#define NCHUNK (BT/CH)    // 1024
#define GPB (TT/CH)       // 128 chunks per sequence

typedef float f4 __attribute__((ext_vector_type(4)));
typedef unsigned u4 __attribute__((ext_vector_type(4)));
typedef short b4 __attribute__((ext_vector_type(4)));
typedef short b8 __attribute__((ext_vector_type(8)));

static __device__ __forceinline__ ushort f2bf(float f) {
  union { float f; unsigned u; } v; v.f = f;
  return (ushort)((v.u + 0x7fffu + ((v.u >> 16) & 1u)) >> 16);  // RNE
}
static __device__ __forceinline__ float bf2f(ushort h) {
  union { unsigned u; float f; } v; v.u = ((unsigned)h) << 16; return v.f;
}

// ---------------- setup: params + FRAGMENT-LINEAR bf16 weights + Lpow (VERBATIM R22) ----
__global__ void k_setup(const float* __restrict__ nu_log, const float* __restrict__ theta_log,
                        const float* __restrict__ gamma_log,
                        const float* __restrict__ B_re, const float* __restrict__ B_im,
                        const float* __restrict__ C_re, const float* __restrict__ C_im,
                        float2* __restrict__ Lc, float2* __restrict__ LCH,
                        float2* __restrict__ Lpow,
                        ushort* __restrict__ BnRe, ushort* __restrict__ BnIm,
                        ushort* __restrict__ CRe, ushort* __restrict__ CIm) {
  int bid = blockIdx.x, tid = threadIdx.x;
  if (bid < NN) {
    int m = bid, n = tid;
    float g = expf(gamma_log[m]);
    int idx = m * NN + n;
    int fidx = ((((m >> 6) * 8 + (n >> 5)) * 4 + ((m >> 4) & 3)) * 64
                + (((n >> 3) & 3) * 16 + (m & 15))) * 8 + (n & 7);
    BnRe[fidx] = f2bf(B_re[idx] * g);
    BnIm[fidx] = f2bf(B_im[idx] * g);
    CRe[fidx]  = f2bf(C_re[idx]);
    CIm[fidx]  = f2bf(-C_im[idx]);   // pre-negated so GEMM2 is pure accumulate
  } else {
    int m = tid;
    float Lmod = expf(-expf(nu_log[m]));
    float th = expf(theta_log[m]);
    float lre = Lmod * cosf(th), lim = Lmod * sinf(th);
    Lc[m] = make_float2(lre, lim);
    float pr = 1.f, pi = 0.f;
    for (int k = 0; k < CH; ++k) {
      Lpow[(size_t)(CH - 1 - k) * NN + m] = make_float2(pr, pi);  // L^k at slot CH-1-k
      float npr = pr * lre - pi * lim;
      pi = pr * lim + pi * lre;
      pr = npr;
    }
    LCH[m] = make_float2(pr, pi);   // L^CH
  }
}

// ---- stage 64x256 x as PACKED BF16 into 32 KB LDS (VERBATIM R19/R22) ----
static __device__ __forceinline__ void stage_x_bf16(const float* __restrict__ xt,
                                                    char* lds, int tid) {
#pragma unroll
  for (int i = 0; i < 16; ++i) {
    int fi = i * 1024 + tid * 4;
    f4 w = *(const f4*)(xt + fi);
    int r = fi >> 8, c = fi & 255;
    int dst = r * 512 + ((c * 2) ^ ((r & 7) << 4));
    b4 p;
    p[0] = (short)f2bf(w[0]); p[1] = (short)f2bf(w[1]);
    p[2] = (short)f2bf(w[2]); p[3] = (short)f2bf(w[3]);
    *(b4*)(lds + dst) = p;
  }
}

// ---- GEMM1 from bf16 LDS tile (512B rows); weights fragment-linear (VERBATIM R22) ----
static __device__ __forceinline__ void gemm1_ldsx_bf(const char* lds,
                                                     const ushort* __restrict__ BnRe,
                                                     const ushort* __restrict__ BnIm,
                                                     int tid, f4 accRe[4][4], f4 accIm[4][4]) {
  int lane = tid & 63, wid = tid >> 6;
  int lr = lane & 15, lg = lane >> 4;
  for (int ks = 0; ks < 8; ++ks) {
    int k0 = ks * 32 + lg * 8;
    b8 a[4];
    for (int mf = 0; mf < 4; ++mf) {
      int r = mf * 16 + lr;
      a[mf] = *(const b8*)(lds + r * 512 + ((k0 * 2) ^ ((r & 7) << 4)));
    }
    for (int nf = 0; nf < 4; ++nf) {
      int fb = (((wid * 8 + ks) * 4 + nf) << 9) + (lane << 3);   // coalesced 1KB/wave
      b8 br = *(const b8*)(BnRe + fb);
      b8 bi = *(const b8*)(BnIm + fb);
      for (int mf = 0; mf < 4; ++mf) {
        accRe[mf][nf] = __builtin_amdgcn_mfma_f32_16x16x32_bf16(a[mf], br, accRe[mf][nf], 0, 0, 0);
        accIm[mf][nf] = __builtin_amdgcn_mfma_f32_16x16x32_bf16(a[mf], bi, accIm[mf][nf], 0, 0, 0);
      }
    }
  }
}

// ---- load one h A-fragment (rowl in 0..31) from packed-u32 LDS ----
static __device__ __forceinline__ void ld_h_frag(const char* lds, int rowl, int k0,
                                                 b8* tr_, b8* ti_) {
  int m4 = (rowl & 7) << 4;
  const char* base = lds + rowl * 1024;
  u4 p0 = *(const u4*)(base + ((k0 * 4) ^ m4));
  u4 p1 = *(const u4*)(base + ((k0 * 4 + 16) ^ m4));
  b8 tr, ti;
  tr[0] = (short)(p0[0] & 0xffffu); ti[0] = (short)(p0[0] >> 16);
  tr[1] = (short)(p0[1] & 0xffffu); ti[1] = (short)(p0[1] >> 16);
  tr[2] = (short)(p0[2] & 0xffffu); ti[2] = (short)(p0[2] >> 16);
  tr[3] = (short)(p0[3] & 0xffffu); ti[3] = (short)(p0[3] >> 16);
  tr[4] = (short)(p1[0] & 0xffffu); ti[4] = (short)(p1[0] >> 16);
  tr[5] = (short)(p1[1] & 0xffffu); ti[5] = (short)(p1[1] >> 16);
  tr[6] = (short)(p1[2] & 0xffffu); ti[6] = (short)(p1[2] >> 16);
  tr[7] = (short)(p1[3] & 0xffffu); ti[7] = (short)(p1[3] >> 16);
  *tr_ = tr; *ti_ = ti;
}

// ---------------- K1: stage x(bf16) -> GEMM1 -> register-scan carry (VERBATIM R22) ----
__global__ __launch_bounds__(256) void k_carry(const float* __restrict__ x,
                                               const ushort* __restrict__ BnRe,
                                               const ushort* __restrict__ BnIm,
                                               const float2* __restrict__ Lc,
                                               const float2* __restrict__ Lpow,
                                               float2* __restrict__ carry) {
  __shared__ char lds[32768];
  int cid = blockIdx.x, tid = threadIdx.x;
  int lane = tid & 63, wid = tid >> 6;
  int lr = lane & 15, lg = lane >> 4;
  int mq = wid * 64;

  float2 pL1[4], pL4[4], pL8[4], pL16[4];
  for (int nf = 0; nf < 4; ++nf) {
    int c = mq + nf * 16 + lr;
    pL1[nf]  = Lc[c];
    pL4[nf]  = Lpow[(size_t)(CH - 1 - 4)  * NN + c];
    pL8[nf]  = Lpow[(size_t)(CH - 1 - 8)  * NN + c];
    pL16[nf] = Lpow[(size_t)(CH - 1 - 16) * NN + c];
  }

  stage_x_bf16(x + (size_t)cid * CH * NN, lds, tid);
  __syncthreads();

  f4 accRe[4][4], accIm[4][4];
  for (int i = 0; i < 4; ++i)
    for (int j = 0; j < 4; ++j) { accRe[i][j] = (f4)0.f; accIm[i][j] = (f4)0.f; }
  gemm1_ldsx_bf(lds, BnRe, BnIm, tid, accRe, accIm);

  for (int nf = 0; nf < 4; ++nf) {
    float2 L1 = pL1[nf], L4 = pL4[nf], L8 = pL8[nf], L16 = pL16[nf];
    float Cr[4], Ci[4];
    for (int mf = 0; mf < 4; ++mf) {
      float cr = accRe[mf][nf][0], ci = accIm[mf][nf][0];
      for (int q = 1; q < 4; ++q) {
        float nr = L1.x * cr - L1.y * ci + accRe[mf][nf][q];
        ci = L1.x * ci + L1.y * cr + accIm[mf][nf][q];
        cr = nr;
      }
      Cr[mf] = cr; Ci[mf] = ci;
    }
    float Hx = 0.f, Hy = 0.f;
    for (int mf = 0; mf < 4; ++mf) {
      float tx = __shfl_up(Cr[mf], 16, 64), ty = __shfl_up(Ci[mf], 16, 64);
      float m1 = (lg >= 1) ? 1.f : 0.f;
      float ax = Cr[mf] + m1 * (L4.x * tx - L4.y * ty);
      float ay = Ci[mf] + m1 * (L4.x * ty + L4.y * tx);
      float ux = __shfl_up(ax, 32, 64), uy = __shfl_up(ay, 32, 64);
      float m2 = (lg >= 2) ? 1.f : 0.f;
      float Ix = ax + m2 * (L8.x * ux - L8.y * uy);
      float Iy = ay + m2 * (L8.x * uy + L8.y * ux);
      float Qx = __shfl(Ix, lr + 48, 64), Qy = __shfl(Iy, lr + 48, 64);
      float nHx = Qx + L16.x * Hx - L16.y * Hy;
      Hy = Qy + L16.x * Hy + L16.y * Hx;
      Hx = nHx;
    }
    if (lg == 0) carry[(size_t)cid * NN + mq + nf * 16 + lr] = make_float2(Hx, Hy);
  }
}

// ---------------- K2: scan carries, in place, 16-wide batched (VERBATIM R22) ----
__global__ void k_seed(float2* __restrict__ carrySeed, const float2* __restrict__ LCH) {
  int b = blockIdx.x, m = threadIdx.x;
  float2 LC = LCH[m];
  float hr = 0.f, hi = 0.f;
  size_t base = (size_t)b * GPB * NN + m;
  for (int g0 = 0; g0 < GPB; g0 += 16) {
    float2 buf[16];
#pragma unroll
    for (int j = 0; j < 16; ++j)
      buf[j] = carrySeed[base + (size_t)(g0 + j) * NN];
#pragma unroll
    for (int j = 0; j < 16; ++j) {
      carrySeed[base + (size_t)(g0 + j) * NN] = make_float2(hr, hi);
      float2 c = buf[j];
      float nr = LC.x * hr - LC.y * hi + c.x;
      hi = LC.x * hi + LC.y * hr + c.y;
      hr = nr;
    }
  }
}

// GEMM2 half with ALL acc indices literal. MFA covers local rows 0..15, MFB 16..31.
#define GEMM2_HALF(MFA, MFB, ROWOFF)                                              \
  {                                                                               \
    __syncthreads();                                                              \
    for (int nf = 0; nf < 4; ++nf)                                                \
      for (int r = 0; r < 4; ++r) {                                               \
        int col = mq + nf * 16 + lr;                                              \
        int rowl = lg * 4 + r;                                                    \
        unsigned p = (unsigned)f2bf(accRe[MFA][nf][r]) |                          \
                     ((unsigned)f2bf(accIm[MFA][nf][r]) << 16);                   \
        *(unsigned*)(lds + rowl * 1024 + ((col * 4) ^ ((rowl & 7) << 4))) = p;    \
        rowl = 16 + lg * 4 + r;                                                   \
        p = (unsigned)f2bf(accRe[MFB][nf][r]) |                                   \
            ((unsigned)f2bf(accIm[MFB][nf][r]) << 16);                            \
        *(unsigned*)(lds + rowl * 1024 + ((col * 4) ^ ((rowl & 7) << 4))) = p;    \
      }                                                                           \
    __syncthreads();                                                              \
    f4 acc0[4], acc1[4];                                                          \
    for (int j = 0; j < 4; ++j) { acc0[j] = (f4)0.f; acc1[j] = (f4)0.f; }         \
    for (int ks = 0; ks < 8; ++ks) {                                              \
      int k0 = ks * 32 + lg * 8;                                                  \
      b8 ar0, ai0, ar1, ai1;                                                      \
      ld_h_frag(lds, lr, k0, &ar0, &ai0);                                         \
      ld_h_frag(lds, 16 + lr, k0, &ar1, &ai1);                                    \
      for (int nf = 0; nf < 4; ++nf) {                                            \
        int fb = (((wid * 8 + ks) * 4 + nf) << 9) + (lane << 3);                  \
        b8 cr = *(const b8*)(CRe + fb);                                           \
        b8 ci = *(const b8*)(CIm + fb);                                           \
        acc0[nf] = __builtin_amdgcn_mfma_f32_16x16x32_bf16(ar0, cr, acc0[nf], 0, 0, 0); \
        acc0[nf] = __builtin_amdgcn_mfma_f32_16x16x32_bf16(ai0, ci, acc0[nf], 0, 0, 0); \
        acc1[nf] = __builtin_amdgcn_mfma_f32_16x16x32_bf16(ar1, cr, acc1[nf], 0, 0, 0); \
        acc1[nf] = __builtin_amdgcn_mfma_f32_16x16x32_bf16(ai1, ci, acc1[nf], 0, 0, 0); \
      }                                                                           \
    }                                                                             \
    for (int nf = 0; nf < 4; ++nf)                                                \
      for (int r = 0; r < 4; ++r) {                                               \
        size_t t0 = rowbase + (ROWOFF) + lg * 4 + r;                              \
        out[t0 * NN + mq + nf * 16 + lr] = acc0[nf][r];                           \
        size_t t1 = rowbase + (ROWOFF) + 16 + lg * 4 + r;                         \
        out[t1 * NN + mq + nf * 16 + lr] = acc1[nf][r];                           \
      }                                                                           \
  }

// ---------------- K3: stage x(bf16,32K) -> GEMM1 -> REG SCAN -> 2x static GEMM2 half ----
__global__ __launch_bounds__(256) void k_out(const float* __restrict__ x,
                                             const ushort* __restrict__ BnRe,
                                             const ushort* __restrict__ BnIm,
                                             const float2* __restrict__ Lc,
                                             const float2* __restrict__ seed,
                                             const ushort* __restrict__ CRe,
                                             const ushort* __restrict__ CIm,
                                             const float2* __restrict__ Lpow,
                                             float* __restrict__ out) {
  __shared__ char lds[32768];
  int cid = blockIdx.x, tid = threadIdx.x;
  size_t rowbase = (size_t)cid * CH;
  int lane = tid & 63, wid = tid >> 6;
  int lr = lane & 15, lg = lane >> 4;
  int mq = wid * 64;

  float2 pL1[4], pL4[4], pL8[4], pL16[4], pw4[4], psd[4];
  for (int nf = 0; nf < 4; ++nf) {
    int c = mq + nf * 16 + lr;
    pL1[nf]  = Lc[c];
    pL4[nf]  = Lpow[(size_t)(CH - 1 - 4)  * NN + c];
    pL8[nf]  = Lpow[(size_t)(CH - 1 - 8)  * NN + c];
    pL16[nf] = Lpow[(size_t)(CH - 1 - 16) * NN + c];
    pw4[nf]  = (lg == 0) ? make_float2(1.f, 0.f)
                         : Lpow[(size_t)(CH - 1 - 4 * lg) * NN + c];  // L^(4lg)
    psd[nf]  = seed[(size_t)cid * NN + c];
  }

  stage_x_bf16(x + rowbase * NN, lds, tid);
  __syncthreads();

  f4 accRe[4][4], accIm[4][4];
  for (int i = 0; i < 4; ++i)
    for (int j = 0; j < 4; ++j) { accRe[i][j] = (f4)0.f; accIm[i][j] = (f4)0.f; }
  gemm1_ldsx_bf(lds, BnRe, BnIm, tid, accRe, accIm);

  // ---- register scan: acc (Bu) -> acc (h)  (VERBATIM R18-R22 algebra) ----
  for (int nf = 0; nf < 4; ++nf) {
    float2 L1 = pL1[nf], L4 = pL4[nf], L8 = pL8[nf], L16 = pL16[nf];
    float2 w4 = pw4[nf], sd = psd[nf];

    float Cr[4], Ci[4];
    for (int mf = 0; mf < 4; ++mf) {
      for (int q = 1; q < 4; ++q) {
        float sr_ = L1.x * accRe[mf][nf][q-1] - L1.y * accIm[mf][nf][q-1] + accRe[mf][nf][q];
        float si_ = L1.x * accIm[mf][nf][q-1] + L1.y * accRe[mf][nf][q-1] + accIm[mf][nf][q];
        accRe[mf][nf][q] = sr_; accIm[mf][nf][q] = si_;
      }
      Cr[mf] = accRe[mf][nf][3]; Ci[mf] = accIm[mf][nf][3];
    }

    float Er[4], Ei[4], Qr[4], Qi[4];
    for (int mf = 0; mf < 4; ++mf) {
      float tx = __shfl_up(Cr[mf], 16, 64), ty = __shfl_up(Ci[mf], 16, 64);
      float m1 = (lg >= 1) ? 1.f : 0.f;
      float ax = Cr[mf] + m1 * (L4.x * tx - L4.y * ty);
      float ay = Ci[mf] + m1 * (L4.x * ty + L4.y * tx);
      float ux = __shfl_up(ax, 32, 64), uy = __shfl_up(ay, 32, 64);
      float m2 = (lg >= 2) ? 1.f : 0.f;
      float Ix = ax + m2 * (L8.x * ux - L8.y * uy);
      float Iy = ay + m2 * (L8.x * uy + L8.y * ux);
      float ex = __shfl_up(Ix, 16, 64), ey = __shfl_up(Iy, 16, 64);
      Er[mf] = m1 * ex; Ei[mf] = m1 * ey;
      Qr[mf] = __shfl(Ix, lr + 48, 64); Qi[mf] = __shfl(Iy, lr + 48, 64);
    }

    float Hx = sd.x, Hy = sd.y;
    for (int mf = 0; mf < 4; ++mf) {
      float Zx = Er[mf] + w4.x * Hx - w4.y * Hy;
      float Zy = Ei[mf] + w4.x * Hy + w4.y * Hx;
      float Wx = L1.x, Wy = L1.y;
      for (int q = 0; q < 4; ++q) {
        float hr_ = accRe[mf][nf][q] + Wx * Zx - Wy * Zy;
        float hi_ = accIm[mf][nf][q] + Wx * Zy + Wy * Zx;
        accRe[mf][nf][q] = hr_; accIm[mf][nf][q] = hi_;
        if (q < 3) { float nWx = Wx * L1.x - Wy * L1.y; Wy = Wx * L1.y + Wy * L1.x; Wx = nWx; }
      }
      float nHx = Qr[mf] + L16.x * Hx - L16.y * Hy;
      Hy = Qi[mf] + L16.x * Hy + L16.y * Hx;
      Hx = nHx;
    }
  }

  GEMM2_HALF(0, 1, 0)    // global rows 0..31
  GEMM2_HALF(2, 3, 32)   // global rows 32..63
}

extern "C" void kernel_launch(void* const* d_in, const int* in_sizes, int n_in,
                              void* d_out, int out_size, void* d_ws, size_t ws_size,
                              hipStream_t stream) {
  const float* x         = (const float*)d_in[0];
  const float* nu_log    = (const float*)d_in[1];
  const float* theta_log = (const float*)d_in[2];
  const float* gamma_log = (const float*)d_in[3];
  const float* B_re      = (const float*)d_in[4];
  const float* B_im      = (const float*)d_in[5];
  const float* C_re      = (const float*)d_in[6];
  const float* C_im      = (const float*)d_in[7];
  float* out = (float*)d_out;

  // d_ws usage: 2,756,608 bytes — VERBATIM layout of all passing rounds.
  char* ws = (char*)d_ws;
  float2*  carrySeed = (float2*)(ws + 0);        // 1024*256*8 = 2,097,152
  float2*  Lc   = (float2*)(ws + 2097152);       // 2,048
  float2*  LCH  = (float2*)(ws + 2099200);       // 2,048
  ushort*  BnRe = (ushort*)(ws + 2101248);       // 131,072 (fragment-linear)
  ushort*  BnIm = (ushort*)(ws + 2232320);       // 131,072
  ushort*  CRe  = (ushort*)(ws + 2363392);       // 131,072
  ushort*  CIm  = (ushort*)(ws + 2494464);       // 131,072  (end 2,625,536)
  float2*  Lpow = (float2*)(ws + 2625536);       // 64*256*8 = 131,072 (end 2,756,608)

  hipLaunchKernelGGL(k_setup, dim3(NN + 1), dim3(NN), 0, stream,
                     nu_log, theta_log, gamma_log, B_re, B_im, C_re, C_im,
                     Lc, LCH, Lpow, BnRe, BnIm, CRe, CIm);
  hipLaunchKernelGGL(k_carry, dim3(NCHUNK), dim3(256), 0, stream,
                     x, BnRe, BnIm, Lc, Lpow, carrySeed);
  hipLaunchKernelGGL(k_seed, dim3(NB), dim3(NN), 0, stream, carrySeed, LCH);
  hipLaunchKernelGGL(k_out, dim3(NCHUNK), dim3(256), 0, stream,
                     x, BnRe, BnIm, Lc, carrySeed, CRe, CIm, Lpow, out);
}

// Round 24
// 167.161 us; speedup vs baseline: 1.0262x; 1.0262x over previous
//
#include <hip/hip_runtime.h>

#define NB 8
#define TT 8192
#define NN 256
#define CH 64             // chunk length (== GEMM M-tile)
#define BT (NB*TT)        // 65536 rows total
#define NCHUNK (BT/CH)    // 1024
#define GPB (TT/CH)       // 128 chunks per sequence

typedef float f4 __attribute__((ext_vector_type(4)));
typedef unsigned u4 __attribute__((ext_vector_type(4)));
typedef short b4 __attribute__((ext_vector_type(4)));
typedef short b8 __attribute__((ext_vector_type(8)));

#define AS1 __attribute__((address_space(1)))
#define AS3 __attribute__((address_space(3)))
static __device__ __forceinline__ void gld16(const void* g, void* l) {
  __builtin_amdgcn_global_load_lds((const AS1 unsigned*)g, (AS3 unsigned*)l, 16, 0, 0);
}

static __device__ __forceinline__ ushort f2bf(float f) {
  union { float f; unsigned u; } v; v.f = f;
  return (ushort)((v.u + 0x7fffu + ((v.u >> 16) & 1u)) >> 16);  // RNE
}
static __device__ __forceinline__ float bf2f(ushort h) {
  union { unsigned u; float f; } v; v.u = ((unsigned)h) << 16; return v.f;
}

// ---------------- setup: params + FRAGMENT-LINEAR bf16 weights + Lpow (VERBATIM R22) ----
// element (m,n) -> fidx = frag*512 + lane*8 + j, frag=((m>>6)*8+(n>>5))*4+((m>>4)&3),
// lane=((n>>3)&3)*16+(m&15), j=n&7.  A wave's (wid,ks,nf) fragment = contiguous 1KB.
__global__ void k_setup(const float* __restrict__ nu_log, const float* __restrict__ theta_log,
                        const float* __restrict__ gamma_log,
                        const float* __restrict__ B_re, const float* __restrict__ B_im,
                        const float* __restrict__ C_re, const float* __restrict__ C_im,
                        float2* __restrict__ Lc, float2* __restrict__ LCH,
                        float2* __restrict__ Lpow,
                        ushort* __restrict__ BnRe, ushort* __restrict__ BnIm,
                        ushort* __restrict__ CRe, ushort* __restrict__ CIm) {
  int bid = blockIdx.x, tid = threadIdx.x;
  if (bid < NN) {
    int m = bid, n = tid;
    float g = expf(gamma_log[m]);
    int idx = m * NN + n;
    int fidx = ((((m >> 6) * 8 + (n >> 5)) * 4 + ((m >> 4) & 3)) * 64
                + (((n >> 3) & 3) * 16 + (m & 15))) * 8 + (n & 7);
    BnRe[fidx] = f2bf(B_re[idx] * g);
    BnIm[fidx] = f2bf(B_im[idx] * g);
    CRe[fidx]  = f2bf(C_re[idx]);
    CIm[fidx]  = f2bf(-C_im[idx]);   // pre-negated so GEMM2 is pure accumulate
  } else {
    int m = tid;
    float Lmod = expf(-expf(nu_log[m]));
    float th = expf(theta_log[m]);
    float lre = Lmod * cosf(th), lim = Lmod * sinf(th);
    Lc[m] = make_float2(lre, lim);
    float pr = 1.f, pi = 0.f;
    for (int k = 0; k < CH; ++k) {
      Lpow[(size_t)(CH - 1 - k) * NN + m] = make_float2(pr, pi);  // L^k at slot CH-1-k
      float npr = pr * lre - pi * lim;
      pi = pr * lim + pi * lre;
      pr = npr;
    }
    LCH[m] = make_float2(pr, pi);   // L^CH
  }
}

// ---- k_carry staging: 64x256 x as PACKED BF16 into 32 KB LDS (VERBATIM R19/R20) ----
static __device__ __forceinline__ void stage_x_bf16(const float* __restrict__ xt,
                                                    char* lds, int tid) {
#pragma unroll
  for (int i = 0; i < 16; ++i) {
    int fi = i * 1024 + tid * 4;
    f4 w = *(const f4*)(xt + fi);
    int r = fi >> 8, c = fi & 255;
    int dst = r * 512 + ((c * 2) ^ ((r & 7) << 4));
    b4 p;
    p[0] = (short)f2bf(w[0]); p[1] = (short)f2bf(w[1]);
    p[2] = (short)f2bf(w[2]); p[3] = (short)f2bf(w[3]);
    *(b4*)(lds + dst) = p;
  }
}

// ---- GEMM1 from bf16 LDS tile (512B rows); weights via fragment-linear loads ----
static __device__ __forceinline__ void gemm1_ldsx_bf(const char* lds,
                                                     const ushort* __restrict__ BnRe,
                                                     const ushort* __restrict__ BnIm,
                                                     int tid, f4 accRe[4][4], f4 accIm[4][4]) {
  int lane = tid & 63, wid = tid >> 6;
  int lr = lane & 15, lg = lane >> 4;
  for (int ks = 0; ks < 8; ++ks) {
    int k0 = ks * 32 + lg * 8;
    b8 a[4];
    for (int mf = 0; mf < 4; ++mf) {
      int r = mf * 16 + lr;
      a[mf] = *(const b8*)(lds + r * 512 + ((k0 * 2) ^ ((r & 7) << 4)));
    }
    for (int nf = 0; nf < 4; ++nf) {
      int fb = (((wid * 8 + ks) * 4 + nf) << 9) + (lane << 3);   // coalesced 1KB/wave
      b8 br = *(const b8*)(BnRe + fb);
      b8 bi = *(const b8*)(BnIm + fb);
      for (int mf = 0; mf < 4; ++mf) {
        accRe[mf][nf] = __builtin_amdgcn_mfma_f32_16x16x32_bf16(a[mf], br, accRe[mf][nf], 0, 0, 0);
        accIm[mf][nf] = __builtin_amdgcn_mfma_f32_16x16x32_bf16(a[mf], bi, accIm[mf][nf], 0, 0, 0);
      }
    }
  }
}

// ---- GEMM1 from fp32 LDS tile (1024B rows, R11 swizzle); weights fragment-linear ----
static __device__ __forceinline__ void gemm1_ldsx_f32(const char* lds,
                                                      const ushort* __restrict__ BnRe,
                                                      const ushort* __restrict__ BnIm,
                                                      int tid, f4 accRe[4][4], f4 accIm[4][4]) {
  int lane = tid & 63, wid = tid >> 6;
  int lr = lane & 15, lg = lane >> 4;
  for (int ks = 0; ks < 8; ++ks) {
    int k0 = ks * 32 + lg * 8;
    b8 a[4];
    for (int mf = 0; mf < 4; ++mf) {
      int r = mf * 16 + lr;
      int sw = (r & 7) << 4;
      const char* base = lds + r * 1024;
      f4 x0 = *(const f4*)(base + ((k0 * 4) ^ sw));
      f4 x1 = *(const f4*)(base + ((k0 * 4 + 16) ^ sw));
      b8 t;
      t[0] = (short)f2bf(x0[0]); t[1] = (short)f2bf(x0[1]);
      t[2] = (short)f2bf(x0[2]); t[3] = (short)f2bf(x0[3]);
      t[4] = (short)f2bf(x1[0]); t[5] = (short)f2bf(x1[1]);
      t[6] = (short)f2bf(x1[2]); t[7] = (short)f2bf(x1[3]);
      a[mf] = t;
    }
    for (int nf = 0; nf < 4; ++nf) {
      int fb = (((wid * 8 + ks) * 4 + nf) << 9) + (lane << 3);   // coalesced 1KB/wave
      b8 br = *(const b8*)(BnRe + fb);
      b8 bi = *(const b8*)(BnIm + fb);
      for (int mf = 0; mf < 4; ++mf) {
        accRe[mf][nf] = __builtin_amdgcn_mfma_f32_16x16x32_bf16(a[mf], br, accRe[mf][nf], 0, 0, 0);
        accIm[mf][nf] = __builtin_amdgcn_mfma_f32_16x16x32_bf16(a[mf], bi, accIm[mf][nf], 0, 0, 0);
      }
    }
  }
}

// ---------------- K1: stage x(bf16) -> GEMM1 -> register-scan carry (VERBATIM R19/R20) ----
__global__ __launch_bounds__(256) void k_carry(const float* __restrict__ x,
                                               const ushort* __restrict__ BnRe,
                                               const ushort* __restrict__ BnIm,
                                               const float2* __restrict__ Lc,
                                               const float2* __restrict__ Lpow,
                                               float2* __restrict__ carry) {
  __shared__ char lds[32768];
  int cid = blockIdx.x, tid = threadIdx.x;
  int lane = tid & 63, wid = tid >> 6;
  int lr = lane & 15, lg = lane >> 4;
  int mq = wid * 64;

  float2 pL1[4], pL4[4], pL8[4], pL16[4];
  for (int nf = 0; nf < 4; ++nf) {
    int c = mq + nf * 16 + lr;
    pL1[nf]  = Lc[c];
    pL4[nf]  = Lpow[(size_t)(CH - 1 - 4)  * NN + c];
    pL8[nf]  = Lpow[(size_t)(CH - 1 - 8)  * NN + c];
    pL16[nf] = Lpow[(size_t)(CH - 1 - 16) * NN + c];
  }

  stage_x_bf16(x + (size_t)cid * CH * NN, lds, tid);
  __syncthreads();

  f4 accRe[4][4], accIm[4][4];
  for (int i = 0; i < 4; ++i)
    for (int j = 0; j < 4; ++j) { accRe[i][j] = (f4)0.f; accIm[i][j] = (f4)0.f; }
  gemm1_ldsx_bf(lds, BnRe, BnIm, tid, accRe, accIm);

  for (int nf = 0; nf < 4; ++nf) {
    float2 L1 = pL1[nf], L4 = pL4[nf], L8 = pL8[nf], L16 = pL16[nf];
    float Cr[4], Ci[4];
    for (int mf = 0; mf < 4; ++mf) {
      float cr = accRe[mf][nf][0], ci = accIm[mf][nf][0];
      for (int q = 1; q < 4; ++q) {
        float nr = L1.x * cr - L1.y * ci + accRe[mf][nf][q];
        ci = L1.x * ci + L1.y * cr + accIm[mf][nf][q];
        cr = nr;
      }
      Cr[mf] = cr; Ci[mf] = ci;
    }
    float Hx = 0.f, Hy = 0.f;
    for (int mf = 0; mf < 4; ++mf) {
      float tx = __shfl_up(Cr[mf], 16, 64), ty = __shfl_up(Ci[mf], 16, 64);
      float m1 = (lg >= 1) ? 1.f : 0.f;
      float ax = Cr[mf] + m1 * (L4.x * tx - L4.y * ty);
      float ay = Ci[mf] + m1 * (L4.x * ty + L4.y * tx);
      float ux = __shfl_up(ax, 32, 64), uy = __shfl_up(ay, 32, 64);
      float m2 = (lg >= 2) ? 1.f : 0.f;
      float Ix = ax + m2 * (L8.x * ux - L8.y * uy);
      float Iy = ay + m2 * (L8.x * uy + L8.y * ux);
      float Qx = __shfl(Ix, lr + 48, 64), Qy = __shfl(Iy, lr + 48, 64);
      float nHx = Qx + L16.x * Hx - L16.y * Hy;
      Hy = Qy + L16.x * Hy + L16.y * Hx;
      Hx = nHx;
    }
    if (lg == 0) carry[(size_t)cid * NN + mq + nf * 16 + lr] = make_float2(Hx, Hy);
  }
}

// ---------------- K2: scan carries, in place, 16-wide batched (VERBATIM R19/R20) ----
__global__ void k_seed(float2* __restrict__ carrySeed, const float2* __restrict__ LCH) {
  int b = blockIdx.x, m = threadIdx.x;
  float2 LC = LCH[m];
  float hr = 0.f, hi = 0.f;
  size_t base = (size_t)b * GPB * NN + m;
  for (int g0 = 0; g0 < GPB; g0 += 16) {
    float2 buf[16];
#pragma unroll
    for (int j = 0; j < 16; ++j)
      buf[j] = carrySeed[base + (size_t)(g0 + j) * NN];
#pragma unroll
    for (int j = 0; j < 16; ++j) {
      carrySeed[base + (size_t)(g0 + j) * NN] = make_float2(hr, hi);
      float2 c = buf[j];
      float nr = LC.x * hr - LC.y * hi + c.x;
      hi = LC.x * hi + LC.y * hr + c.y;
      hr = nr;
    }
  }
}

// ---------------- K3: gld16-stage x(fp32) -> GEMM1 -> REG SCAN -> pack h -> GEMM2 (R20) ----
__global__ __launch_bounds__(256) void k_out(const float* __restrict__ x,
                                             const ushort* __restrict__ BnRe,
                                             const ushort* __restrict__ BnIm,
                                             const float2* __restrict__ Lc,
                                             const float2* __restrict__ seed,
                                             const ushort* __restrict__ CRe,
                                             const ushort* __restrict__ CIm,
                                             const float2* __restrict__ Lpow,
                                             float* __restrict__ out) {
  __shared__ char lds[65536];
  int cid = blockIdx.x, tid = threadIdx.x;
  size_t rowbase = (size_t)cid * CH;
  int lane = tid & 63, wid = tid >> 6;
  int lr = lane & 15, lg = lane >> 4;
  int mq = wid * 64;

  { // async staging: LDS dest linear, global source inverse-swizzled (rule #21, R20)
    const char* xb = (const char*)(x + rowbase * NN);
#pragma unroll
    for (int i = 0; i < 16; ++i) {
      int r = i * 4 + wid;
      int src = r * 1024 + ((lane * 16) ^ ((r & 7) << 4));
      int dst = r * 1024 + lane * 16;
      gld16(xb + src, lds + dst);
    }
  }

  float2 pL1[4], pL4[4], pL8[4], pL16[4], pw4[4], psd[4];
  for (int nf = 0; nf < 4; ++nf) {
    int c = mq + nf * 16 + lr;
    pL1[nf]  = Lc[c];
    pL4[nf]  = Lpow[(size_t)(CH - 1 - 4)  * NN + c];
    pL8[nf]  = Lpow[(size_t)(CH - 1 - 8)  * NN + c];
    pL16[nf] = Lpow[(size_t)(CH - 1 - 16) * NN + c];
    pw4[nf]  = (lg == 0) ? make_float2(1.f, 0.f)
                         : Lpow[(size_t)(CH - 1 - 4 * lg) * NN + c];  // L^(4lg)
    psd[nf]  = seed[(size_t)cid * NN + c];
  }
  __syncthreads();   // drains vmcnt (gld16 complete)

  f4 accRe[4][4], accIm[4][4];
  for (int i = 0; i < 4; ++i)
    for (int j = 0; j < 4; ++j) { accRe[i][j] = (f4)0.f; accIm[i][j] = (f4)0.f; }
  gemm1_ldsx_f32(lds, BnRe, BnIm, tid, accRe, accIm);

  // ---- register scan: acc (Bu) -> acc (h)  (VERBATIM R18/R19/R20 algebra) ----
  for (int nf = 0; nf < 4; ++nf) {
    float2 L1 = pL1[nf], L4 = pL4[nf], L8 = pL8[nf], L16 = pL16[nf];
    float2 w4 = pw4[nf], sd = psd[nf];

    float Cr[4], Ci[4];
    for (int mf = 0; mf < 4; ++mf) {
      for (int q = 1; q < 4; ++q) {
        float sr_ = L1.x * accRe[mf][nf][q-1] - L1.y * accIm[mf][nf][q-1] + accRe[mf][nf][q];
        float si_ = L1.x * accIm[mf][nf][q-1] + L1.y * accRe[mf][nf][q-1] + accIm[mf][nf][q];
        accRe[mf][nf][q] = sr_; accIm[mf][nf][q] = si_;
      }
      Cr[mf] = accRe[mf][nf][3]; Ci[mf] = accIm[mf][nf][3];
    }

    float Er[4], Ei[4], Qr[4], Qi[4];
    for (int mf = 0; mf < 4; ++mf) {
      float tx = __shfl_up(Cr[mf], 16, 64), ty = __shfl_up(Ci[mf], 16, 64);
      float m1 = (lg >= 1) ? 1.f : 0.f;
      float ax = Cr[mf] + m1 * (L4.x * tx - L4.y * ty);
      float ay = Ci[mf] + m1 * (L4.x * ty + L4.y * tx);
      float ux = __shfl_up(ax, 32, 64), uy = __shfl_up(ay, 32, 64);
      float m2 = (lg >= 2) ? 1.f : 0.f;
      float Ix = ax + m2 * (L8.x * ux - L8.y * uy);
      float Iy = ay + m2 * (L8.x * uy + L8.y * ux);
      float ex = __shfl_up(Ix, 16, 64), ey = __shfl_up(Iy, 16, 64);
      Er[mf] = m1 * ex; Ei[mf] = m1 * ey;
      Qr[mf] = __shfl(Ix, lr + 48, 64); Qi[mf] = __shfl(Iy, lr + 48, 64);
    }

    float Hx = sd.x, Hy = sd.y;
    for (int mf = 0; mf < 4; ++mf) {
      float Zx = Er[mf] + w4.x * Hx - w4.y * Hy;
      float Zy = Ei[mf] + w4.x * Hy + w4.y * Hx;
      float Wx = L1.x, Wy = L1.y;
      for (int q = 0; q < 4; ++q) {
        float hr_ = accRe[mf][nf][q] + Wx * Zx - Wy * Zy;
        float hi_ = accIm[mf][nf][q] + Wx * Zy + Wy * Zx;
        accRe[mf][nf][q] = hr_; accIm[mf][nf][q] = hi_;
        if (q < 3) { float nWx = Wx * L1.x - Wy * L1.y; Wy = Wx * L1.y + Wy * L1.x; Wx = nWx; }
      }
      float nHx = Qr[mf] + L16.x * Hx - L16.y * Hy;
      Hy = Qi[mf] + L16.x * Hy + L16.y * Hx;
      Hx = nHx;
    }
  }
  __syncthreads();   // all GEMM1 LDS reads done before h overwrites the x tile

  for (int mf = 0; mf < 4; ++mf)      // packed h store (VERBATIM R11 formula)
    for (int nf = 0; nf < 4; ++nf)
      for (int r = 0; r < 4; ++r) {
        int row = mf * 16 + lg * 4 + r;
        int col = mq + nf * 16 + lr;
        unsigned p = (unsigned)f2bf(accRe[mf][nf][r]) | ((unsigned)f2bf(accIm[mf][nf][r]) << 16);
        int off = row * 1024 + ((col * 4) ^ ((row & 7) << 4));
        *(unsigned*)(lds + off) = p;
      }
  __syncthreads();

  // GEMM2 (full 64-row tile; fragment-linear C loads)
  f4 acc[4][4];
  for (int i = 0; i < 4; ++i)
    for (int j = 0; j < 4; ++j) acc[i][j] = (f4)0.f;

  for (int ks = 0; ks < 8; ++ks) {
    int k0 = ks * 32 + lg * 8;
    b8 ar[4], ai[4];
    for (int mf = 0; mf < 4; ++mf) {
      int row = mf * 16 + lr;
      int m4 = (row & 7) << 4;
      const char* base = lds + row * 1024;
      u4 p0 = *(const u4*)(base + ((k0 * 4) ^ m4));
      u4 p1 = *(const u4*)(base + ((k0 * 4 + 16) ^ m4));
      b8 tr, ti;
      tr[0] = (short)(p0[0] & 0xffffu); ti[0] = (short)(p0[0] >> 16);
      tr[1] = (short)(p0[1] & 0xffffu); ti[1] = (short)(p0[1] >> 16);
      tr[2] = (short)(p0[2] & 0xffffu); ti[2] = (short)(p0[2] >> 16);
      tr[3] = (short)(p0[3] & 0xffffu); ti[3] = (short)(p0[3] >> 16);
      tr[4] = (short)(p1[0] & 0xffffu); ti[4] = (short)(p1[0] >> 16);
      tr[5] = (short)(p1[1] & 0xffffu); ti[5] = (short)(p1[1] >> 16);
      tr[6] = (short)(p1[2] & 0xffffu); ti[6] = (short)(p1[2] >> 16);
      tr[7] = (short)(p1[3] & 0xffffu); ti[7] = (short)(p1[3] >> 16);
      ar[mf] = tr; ai[mf] = ti;
    }
    for (int nf = 0; nf < 4; ++nf) {
      int fb = (((wid * 8 + ks) * 4 + nf) << 9) + (lane << 3);   // coalesced 1KB/wave
      b8 cr = *(const b8*)(CRe + fb);
      b8 ci = *(const b8*)(CIm + fb);
      for (int mf = 0; mf < 4; ++mf) {
        acc[mf][nf] = __builtin_amdgcn_mfma_f32_16x16x32_bf16(ar[mf], cr, acc[mf][nf], 0, 0, 0);
        acc[mf][nf] = __builtin_amdgcn_mfma_f32_16x16x32_bf16(ai[mf], ci, acc[mf][nf], 0, 0, 0);
      }
    }
  }
  for (int mf = 0; mf < 4; ++mf)
    for (int nf = 0; nf < 4; ++nf)
      for (int r = 0; r < 4; ++r) {
        size_t t = rowbase + mf * 16 + lg * 4 + r;
        out[t * NN + mq + nf * 16 + lr] = acc[mf][nf][r];
      }
}

extern "C" void kernel_launch(void* const* d_in, const int* in_sizes, int n_in,
                              void* d_out, int out_size, void* d_ws, size_t ws_size,
                              hipStream_t stream) {
  const float* x         = (const float*)d_in[0];
  const float* nu_log    = (const float*)d_in[1];
  const float* theta_log = (const float*)d_in[2];
  const float* gamma_log = (const float*)d_in[3];
  const float* B_re      = (const float*)d_in[4];
  const float* B_im      = (const float*)d_in[5];
  const float* C_re      = (const float*)d_in[6];
  const float* C_im      = (const float*)d_in[7];
  float* out = (float*)d_out;

  // d_ws usage: 2,756,608 bytes — VERBATIM layout of all passing rounds.
  char* ws = (char*)d_ws;
  float2*  carrySeed = (float2*)(ws + 0);        // 1024*256*8 = 2,097,152
  float2*  Lc   = (float2*)(ws + 2097152);       // 2,048
  float2*  LCH  = (float2*)(ws + 2099200);       // 2,048
  ushort*  BnRe = (ushort*)(ws + 2101248);       // 131,072 (fragment-linear)
  ushort*  BnIm = (ushort*)(ws + 2232320);       // 131,072
  ushort*  CRe  = (ushort*)(ws + 2363392);       // 131,072
  ushort*  CIm  = (ushort*)(ws + 2494464);       // 131,072  (end 2,625,536)
  float2*  Lpow = (float2*)(ws + 2625536);       // 64*256*8 = 131,072 (end 2,756,608)

  hipLaunchKernelGGL(k_setup, dim3(NN + 1), dim3(NN), 0, stream,
                     nu_log, theta_log, gamma_log, B_re, B_im, C_re, C_im,
                     Lc, LCH, Lpow, BnRe, BnIm, CRe, CIm);
  hipLaunchKernelGGL(k_carry, dim3(NCHUNK), dim3(256), 0, stream,
                     x, BnRe, BnIm, Lc, Lpow, carrySeed);
  hipLaunchKernelGGL(k_seed, dim3(NB), dim3(NN), 0, stream, carrySeed, LCH);
  hipLaunchKernelGGL(k_out, dim3(NCHUNK), dim3(256), 0, stream,
                     x, BnRe, BnIm, Lc, carrySeed, CRe, CIm, Lpow, out);
}